// Round 2
// baseline (1216.876 us; speedup 1.0000x reference)
//
#include <hip/hip_runtime.h>

#define LEAK 0.2f

// ---------------- CSR build (incoming edges per dst) ----------------
__global__ void count_kernel(const int* __restrict__ dstp, int* __restrict__ cnt, int E) {
  int e = blockIdx.x * blockDim.x + threadIdx.x;
  if (e < E) atomicAdd(&cnt[dstp[e]], 1);
}

__global__ void scan_kernel(const int* __restrict__ cnt, int* __restrict__ rowptr, int n) {
  __shared__ int part[1024];
  int t = threadIdx.x;
  int chunk = (n + 1023) >> 10;
  int lo = t * chunk, hi = lo + chunk;
  if (hi > n) hi = n;
  if (lo > n) lo = n;
  int s = 0;
  for (int i = lo; i < hi; ++i) s += cnt[i];
  part[t] = s;
  __syncthreads();
  for (int off = 1; off < 1024; off <<= 1) {
    int v = 0;
    if (t >= off) v = part[t - off];
    __syncthreads();
    if (t >= off) part[t] += v;
    __syncthreads();
  }
  int base = (t == 0) ? 0 : part[t - 1];
  for (int i = lo; i < hi; ++i) { rowptr[i] = base; base += cnt[i]; }
  if (t == 1023) rowptr[n] = part[1023];
}

__global__ void fill_kernel(const int* __restrict__ srcp, const int* __restrict__ dstp,
                            const int* __restrict__ rowptr, int* __restrict__ cur,
                            int* __restrict__ csr_src, int E) {
  int e = blockIdx.x * blockDim.x + threadIdx.x;
  if (e < E) {
    int d = dstp[e];
    int pos = atomicAdd(&cur[d], 1);
    csr_src[rowptr[d] + pos] = srcp[e];
  }
}

// ---------- GEMM: C[M,NOUT] = A[M,128] @ W[128,NOUT] + bias, optional ReLU ----------
// W staged in LDS (64KB max -> 2 blocks/CU). A read direct from global (block's
// 64x128 tile = 32KB, L1-resident; 16 lanes broadcast-coalesce each address).
// In-place safe (C==A): each block reads only the rows it writes; __syncthreads()
// fences all A reads before any C write.
template<int NOUT, bool RELU>
__global__ __launch_bounds__(256)
void gemm_k128(const float* __restrict__ A, const float* __restrict__ W,
               const float* __restrict__ bias, float* __restrict__ C, int M) {
  constexpr int TN = NOUT / 16;  // 8 (NOUT=128) or 4 (NOUT=64)
  __shared__ float Ws[128 * NOUT];
  int tid = threadIdx.x;
  for (int i = tid * 4; i < 128 * NOUT; i += 256 * 4)
    *(float4*)&Ws[i] = *(const float4*)&W[i];
  __syncthreads();

  int row0 = blockIdx.x * 64;
  int rg = tid >> 4, cg = tid & 15;
  int r[4];
#pragma unroll
  for (int i = 0; i < 4; ++i) { int rr = row0 + rg * 4 + i; r[i] = rr < M ? rr : M - 1; }

  float acc[4][TN];
#pragma unroll
  for (int i = 0; i < 4; ++i)
#pragma unroll
    for (int j = 0; j < TN; ++j) acc[i][j] = 0.f;

#pragma unroll 2
  for (int k4 = 0; k4 < 32; ++k4) {
    float4 a[4];
#pragma unroll
    for (int i = 0; i < 4; ++i) a[i] = *(const float4*)&A[(size_t)r[i] * 128 + k4 * 4];
#pragma unroll
    for (int kk = 0; kk < 4; ++kk) {
      float b[TN];
#pragma unroll
      for (int j4 = 0; j4 < TN / 4; ++j4)
        *(float4*)&b[j4 * 4] = *(const float4*)&Ws[(k4 * 4 + kk) * NOUT + cg * TN + j4 * 4];
#pragma unroll
      for (int i = 0; i < 4; ++i) {
        float av = ((const float*)&a[i])[kk];
#pragma unroll
        for (int j = 0; j < TN; ++j) acc[i][j] += av * b[j];
      }
    }
  }

  float bv[TN];
#pragma unroll
  for (int j4 = 0; j4 < TN / 4; ++j4)
    *(float4*)&bv[j4 * 4] = *(const float4*)&bias[cg * TN + j4 * 4];

  __syncthreads();  // in-place fence: all A reads done before any C write
#pragma unroll
  for (int i = 0; i < 4; ++i) {
    int rr = row0 + rg * 4 + i;
    if (rr < M) {
#pragma unroll
      for (int j4 = 0; j4 < TN / 4; ++j4) {
        float4 o;
        float* op = (float*)&o;
#pragma unroll
        for (int q = 0; q < 4; ++q) {
          float v = acc[i][j4 * 4 + q] + bv[j4 * 4 + q];
          if (RELU) v = fmaxf(v, 0.f);
          op[q] = v;
        }
        *(float4*)&C[(size_t)rr * NOUT + cg * TN + j4 * 4] = o;
      }
    }
  }
}

// ---------- GATv2 aggregation: one wave per node ----------
// Per node: xr row resident in regs (2 floats/lane). Loop incoming edges
// (self-loop first): gather xl[src] once, logit = per-head dot via shfl_xor
// reduce, w = exp(logit) (no max-subtraction: |logit| small), online
// accumulate acc += w*xl, denom += w. Epilogue: /denom + gat bias + skip (+ReLU).
// out may alias skip (read own row before write; node-exclusive).
template<int H>
__global__ __launch_bounds__(256)
void gat_agg(const float* __restrict__ xl, const float* __restrict__ xr,
             const float* __restrict__ skip, const float* __restrict__ att,
             const float* __restrict__ gbias, const int* __restrict__ rowptr,
             const int* __restrict__ csr_src, float* __restrict__ out,
             int n, int relu) {
  constexpr int C = 128 / H;  // channels per head
  constexpr int G = C / 2;    // lanes per head-group (2 floats/lane)
  int wid = blockIdx.x * (blockDim.x >> 6) + (threadIdx.x >> 6);
  if (wid >= n) return;
  int lane = threadIdx.x & 63;
  size_t base = (size_t)wid * 128 + lane * 2;
  float2 xrv = *(const float2*)(xr + base);
  float2 av = *(const float2*)(att + lane * 2);  // att flat [H*C]=[128]
  float2 acc = make_float2(0.f, 0.f);
  float denom = 0.f;
  int e0 = rowptr[wid], e1 = rowptr[wid + 1];
  for (int idx = e0 - 1; idx < e1; ++idx) {
    int src = (idx < e0) ? wid : csr_src[idx];  // idx==e0-1 -> self loop
    float2 xlv = *(const float2*)(xl + (size_t)src * 128 + lane * 2);
    float ex = xlv.x + xrv.x; ex = ex > 0.f ? ex : LEAK * ex;
    float ey = xlv.y + xrv.y; ey = ey > 0.f ? ey : LEAK * ey;
    float p = ex * av.x + ey * av.y;
#pragma unroll
    for (int o = 1; o < G; o <<= 1) p += __shfl_xor(p, o, 64);
    float w = __expf(p);
    denom += w;
    acc.x += w * xlv.x;
    acc.y += w * xlv.y;
  }
  float inv = 1.f / denom;
  float2 sk = *(const float2*)(skip + base);
  float2 gb = *(const float2*)(gbias + lane * 2);
  float ox = acc.x * inv + gb.x + sk.x;
  float oy = acc.y * inv + gb.y + sk.y;
  if (relu) { ox = fmaxf(ox, 0.f); oy = fmaxf(oy, 0.f); }
  *(float2*)(out + base) = make_float2(ox, oy);
}

extern "C" void kernel_launch(void* const* d_in, const int* in_sizes, int n_in,
                              void* d_out, int out_size, void* d_ws, size_t ws_size,
                              hipStream_t stream) {
  const float* x       = (const float*)d_in[0];
  const int* ei        = (const int*)d_in[1];   // int32 (harness converts int64 -> int)
  const float* Wl1     = (const float*)d_in[2];
  const float* bl1     = (const float*)d_in[3];
  const float* Wr1     = (const float*)d_in[4];
  const float* br1     = (const float*)d_in[5];
  const float* att1    = (const float*)d_in[6];
  const float* b1      = (const float*)d_in[7];
  const float* Wl2     = (const float*)d_in[8];
  const float* bl2     = (const float*)d_in[9];
  const float* Wr2     = (const float*)d_in[10];
  const float* br2     = (const float*)d_in[11];
  const float* att2    = (const float*)d_in[12];
  const float* b2      = (const float*)d_in[13];
  const float* skip1_w = (const float*)d_in[14];
  const float* skip1_b = (const float*)d_in[15];
  const float* skip2_w = (const float*)d_in[16];
  const float* skip2_b = (const float*)d_in[17];
  const float* mlp1_w  = (const float*)d_in[18];
  const float* mlp1_b  = (const float*)d_in[19];
  const float* mlp2_w  = (const float*)d_in[20];
  const float* mlp2_b  = (const float*)d_in[21];

  const int N = in_sizes[0] / 128;
  const int E = in_sizes[1] / 2;
  float* out = (float*)d_out;

  char* ws = (char*)d_ws;
  size_t off = 0;
  auto alloc = [&](size_t bytes) -> void* {
    void* p = ws + off;
    off = (off + bytes + 255) & ~(size_t)255;
    return p;
  };
  int* rowptr  = (int*)alloc((size_t)(N + 1) * sizeof(int));
  int* cnt     = (int*)alloc((size_t)N * sizeof(int));
  int* csr_src = (int*)alloc((size_t)E * sizeof(int));
  float* bufA  = (float*)alloc((size_t)N * 128 * sizeof(float));
  float* bufB  = (float*)alloc((size_t)N * 128 * sizeof(float));
  float* bufC  = (float*)alloc((size_t)N * 128 * sizeof(float));

  const int* srcp = ei;
  const int* dstp = ei + E;

  const int egrid = (E + 255) / 256;
  const int ggrid = (N + 63) / 64;
  const int agrid = (N + 3) / 4;

  // CSR by dst (shared by both GAT layers)
  hipMemsetAsync(cnt, 0, (size_t)N * sizeof(int), stream);
  count_kernel<<<egrid, 256, 0, stream>>>(dstp, cnt, E);
  scan_kernel<<<1, 1024, 0, stream>>>(cnt, rowptr, N);
  hipMemsetAsync(cnt, 0, (size_t)N * sizeof(int), stream);
  fill_kernel<<<egrid, 256, 0, stream>>>(srcp, dstp, rowptr, cnt, csr_src, E);

  // ---- Layer 1: GATv2(128 -> 4x32 concat) + skip + ReLU ----
  gemm_k128<128, false><<<ggrid, 256, 0, stream>>>(x, Wl1, bl1, bufA, N);      // xl1
  gemm_k128<128, false><<<ggrid, 256, 0, stream>>>(x, Wr1, br1, bufB, N);      // xr1
  gemm_k128<128, false><<<ggrid, 256, 0, stream>>>(x, skip1_w, skip1_b, bufC, N); // skip1
  gat_agg<4><<<agrid, 256, 0, stream>>>(bufA, bufB, bufC, att1, b1,
                                        rowptr, csr_src, bufC, N, 1);          // h -> bufC

  // ---- Layer 2: GATv2(128 -> 128, 1 head) + skip ----
  gemm_k128<128, false><<<ggrid, 256, 0, stream>>>(bufC, Wl2, bl2, bufA, N);   // xl2
  gemm_k128<128, false><<<ggrid, 256, 0, stream>>>(bufC, Wr2, br2, bufB, N);   // xr2
  gemm_k128<128, false><<<ggrid, 256, 0, stream>>>(bufC, skip2_w, skip2_b, bufC, N); // skip2 in-place
  gat_agg<1><<<agrid, 256, 0, stream>>>(bufA, bufB, bufC, att2, b2,
                                        rowptr, csr_src, bufC, N, 0);          // out2 -> bufC

  // ---- MLP head ----
  gemm_k128<128, true><<<ggrid, 256, 0, stream>>>(bufC, mlp1_w, mlp1_b, bufA, N);
  gemm_k128<64, false><<<ggrid, 256, 0, stream>>>(bufA, mlp2_w, mlp2_b, out, N);
}

// Round 3
// 982.625 us; speedup vs baseline: 1.2384x; 1.2384x over previous
//
#include <hip/hip_runtime.h>

#define LEAK 0.2f

// ---------------- CSR build (incoming edges per dst) ----------------
__global__ void count_kernel(const int* __restrict__ dstp, int* __restrict__ cnt, int E) {
  int e = blockIdx.x * blockDim.x + threadIdx.x;
  if (e < E) atomicAdd(&cnt[dstp[e]], 1);
}

__global__ void scan_kernel(const int* __restrict__ cnt, int* __restrict__ rowptr, int n) {
  __shared__ int part[1024];
  int t = threadIdx.x;
  int chunk = (n + 1023) >> 10;
  int lo = t * chunk, hi = lo + chunk;
  if (hi > n) hi = n;
  if (lo > n) lo = n;
  int s = 0;
  for (int i = lo; i < hi; ++i) s += cnt[i];
  part[t] = s;
  __syncthreads();
  for (int off = 1; off < 1024; off <<= 1) {
    int v = 0;
    if (t >= off) v = part[t - off];
    __syncthreads();
    if (t >= off) part[t] += v;
    __syncthreads();
  }
  int base = (t == 0) ? 0 : part[t - 1];
  for (int i = lo; i < hi; ++i) { rowptr[i] = base; base += cnt[i]; }
  if (t == 1023) rowptr[n] = part[1023];
}

__global__ void fill_kernel(const int* __restrict__ srcp, const int* __restrict__ dstp,
                            const int* __restrict__ rowptr, int* __restrict__ cur,
                            int* __restrict__ csr_src, int E) {
  int e = blockIdx.x * blockDim.x + threadIdx.x;
  if (e < E) {
    int d = dstp[e];
    int pos = atomicAdd(&cur[d], 1);
    csr_src[rowptr[d] + pos] = srcp[e];
  }
}

// ---------- GEMM: C[M,NOUT] = A[M,128] @ W[128,NOUT] + bias, optional ReLU ----------
// W staged in LDS in two 64-k chunks (32 KB for NOUT=128) -> 5 blocks/CU (20
// waves/CU) vs 2 blocks with monolithic 64 KB stage. A read direct from global
// (block's 64x128 tile = 32KB, L1-resident; 16 lanes broadcast-coalesce).
// In-place safe (C==A): each block reads only rows it writes; chunk-end
// __syncthreads() fences all A reads before the C write.
template<int NOUT, bool RELU>
__global__ __launch_bounds__(256)
void gemm_k128(const float* __restrict__ A, const float* __restrict__ W,
               const float* __restrict__ bias, float* __restrict__ C, int M) {
  constexpr int TN = NOUT / 16;  // 8 (NOUT=128) or 4 (NOUT=64)
  constexpr int KC = 64;
  __shared__ float Ws[KC * NOUT];
  int tid = threadIdx.x;
  int row0 = blockIdx.x * 64;
  int rg = tid >> 4, cg = tid & 15;
  int r[4];
#pragma unroll
  for (int i = 0; i < 4; ++i) { int rr = row0 + rg * 4 + i; r[i] = rr < M ? rr : M - 1; }

  float acc[4][TN];
#pragma unroll
  for (int i = 0; i < 4; ++i)
#pragma unroll
    for (int j = 0; j < TN; ++j) acc[i][j] = 0.f;

  for (int kc = 0; kc < 128; kc += KC) {
    for (int i = tid * 4; i < KC * NOUT; i += 256 * 4)
      *(float4*)&Ws[i] = *(const float4*)&W[kc * NOUT + i];
    __syncthreads();

#pragma unroll 4
    for (int k4 = 0; k4 < KC / 4; ++k4) {
      float4 a[4];
#pragma unroll
      for (int i = 0; i < 4; ++i) a[i] = *(const float4*)&A[(size_t)r[i] * 128 + kc + k4 * 4];
#pragma unroll
      for (int kk = 0; kk < 4; ++kk) {
        float b[TN];
#pragma unroll
        for (int j4 = 0; j4 < TN / 4; ++j4)
          *(float4*)&b[j4 * 4] = *(const float4*)&Ws[(k4 * 4 + kk) * NOUT + cg * TN + j4 * 4];
#pragma unroll
        for (int i = 0; i < 4; ++i) {
          float av = ((const float*)&a[i])[kk];
#pragma unroll
          for (int j = 0; j < TN; ++j) acc[i][j] += av * b[j];
        }
      }
    }
    __syncthreads();  // fences A reads of this chunk; also before restage
  }

  float bv[TN];
#pragma unroll
  for (int j4 = 0; j4 < TN / 4; ++j4)
    *(float4*)&bv[j4 * 4] = *(const float4*)&bias[cg * TN + j4 * 4];

#pragma unroll
  for (int i = 0; i < 4; ++i) {
    int rr = row0 + rg * 4 + i;
    if (rr < M) {
#pragma unroll
      for (int j4 = 0; j4 < TN / 4; ++j4) {
        float4 o;
        float* op = (float*)&o;
#pragma unroll
        for (int q = 0; q < 4; ++q) {
          float v = acc[i][j4 * 4 + q] + bv[j4 * 4 + q];
          if (RELU) v = fmaxf(v, 0.f);
          op[q] = v;
        }
        *(float4*)&C[(size_t)rr * NOUT + cg * TN + j4 * 4] = o;
      }
    }
  }
}

// ---------- GATv2 aggregation: one wave per node, 4 edges in flight ----------
// Self-loop peeled. Main loop unrolled x4: 4 csr indices + 4 independent row
// gathers issued back-to-back (4x memory-level parallelism vs serial chain),
// then 4 interleaved shuffle-reduce chains, 4 exp, online accumulate.
// out may alias skip (node-exclusive row, read-before-write).
template<int H>
__global__ __launch_bounds__(256)
void gat_agg(const float* __restrict__ xl, const float* __restrict__ xr,
             const float* __restrict__ skip, const float* __restrict__ att,
             const float* __restrict__ gbias, const int* __restrict__ rowptr,
             const int* __restrict__ csr_src, float* __restrict__ out,
             int n, int relu) {
  constexpr int C = 128 / H;  // channels per head
  constexpr int G = C / 2;    // lanes per head-group (2 floats/lane)
  int wid = blockIdx.x * (blockDim.x >> 6) + (threadIdx.x >> 6);
  if (wid >= n) return;
  int lane = threadIdx.x & 63;
  size_t base = (size_t)wid * 128 + lane * 2;
  float2 xrv = *(const float2*)(xr + base);
  float2 av = *(const float2*)(att + lane * 2);  // att flat [H*C]=[128]
  float2 acc = make_float2(0.f, 0.f);
  float denom = 0.f;
  int e0 = rowptr[wid], e1 = rowptr[wid + 1];

  // self-loop
  {
    float2 xlv = *(const float2*)(xl + base);
    float ex = xlv.x + xrv.x; ex = ex > 0.f ? ex : LEAK * ex;
    float ey = xlv.y + xrv.y; ey = ey > 0.f ? ey : LEAK * ey;
    float p = ex * av.x + ey * av.y;
#pragma unroll
    for (int o = 1; o < G; o <<= 1) p += __shfl_xor(p, o, 64);
    float w = __expf(p);
    denom += w;
    acc.x += w * xlv.x;
    acc.y += w * xlv.y;
  }

  int idx = e0;
  for (; idx + 4 <= e1; idx += 4) {
    int s0 = csr_src[idx], s1 = csr_src[idx + 1], s2 = csr_src[idx + 2], s3 = csr_src[idx + 3];
    float2 v0 = *(const float2*)(xl + (size_t)s0 * 128 + lane * 2);
    float2 v1 = *(const float2*)(xl + (size_t)s1 * 128 + lane * 2);
    float2 v2 = *(const float2*)(xl + (size_t)s2 * 128 + lane * 2);
    float2 v3 = *(const float2*)(xl + (size_t)s3 * 128 + lane * 2);
    float ex, ey;
    ex = v0.x + xrv.x; ex = ex > 0.f ? ex : LEAK * ex;
    ey = v0.y + xrv.y; ey = ey > 0.f ? ey : LEAK * ey;
    float p0 = ex * av.x + ey * av.y;
    ex = v1.x + xrv.x; ex = ex > 0.f ? ex : LEAK * ex;
    ey = v1.y + xrv.y; ey = ey > 0.f ? ey : LEAK * ey;
    float p1 = ex * av.x + ey * av.y;
    ex = v2.x + xrv.x; ex = ex > 0.f ? ex : LEAK * ex;
    ey = v2.y + xrv.y; ey = ey > 0.f ? ey : LEAK * ey;
    float p2 = ex * av.x + ey * av.y;
    ex = v3.x + xrv.x; ex = ex > 0.f ? ex : LEAK * ex;
    ey = v3.y + xrv.y; ey = ey > 0.f ? ey : LEAK * ey;
    float p3 = ex * av.x + ey * av.y;
#pragma unroll
    for (int o = 1; o < G; o <<= 1) {
      p0 += __shfl_xor(p0, o, 64);
      p1 += __shfl_xor(p1, o, 64);
      p2 += __shfl_xor(p2, o, 64);
      p3 += __shfl_xor(p3, o, 64);
    }
    float w0 = __expf(p0), w1 = __expf(p1), w2 = __expf(p2), w3 = __expf(p3);
    denom += (w0 + w1) + (w2 + w3);
    acc.x += w0 * v0.x + w1 * v1.x + w2 * v2.x + w3 * v3.x;
    acc.y += w0 * v0.y + w1 * v1.y + w2 * v2.y + w3 * v3.y;
  }
  for (; idx < e1; ++idx) {
    int src = csr_src[idx];
    float2 xlv = *(const float2*)(xl + (size_t)src * 128 + lane * 2);
    float ex = xlv.x + xrv.x; ex = ex > 0.f ? ex : LEAK * ex;
    float ey = xlv.y + xrv.y; ey = ey > 0.f ? ey : LEAK * ey;
    float p = ex * av.x + ey * av.y;
#pragma unroll
    for (int o = 1; o < G; o <<= 1) p += __shfl_xor(p, o, 64);
    float w = __expf(p);
    denom += w;
    acc.x += w * xlv.x;
    acc.y += w * xlv.y;
  }

  float inv = 1.f / denom;
  float2 sk = *(const float2*)(skip + base);
  float2 gb = *(const float2*)(gbias + lane * 2);
  float ox = acc.x * inv + gb.x + sk.x;
  float oy = acc.y * inv + gb.y + sk.y;
  if (relu) { ox = fmaxf(ox, 0.f); oy = fmaxf(oy, 0.f); }
  *(float2*)(out + base) = make_float2(ox, oy);
}

extern "C" void kernel_launch(void* const* d_in, const int* in_sizes, int n_in,
                              void* d_out, int out_size, void* d_ws, size_t ws_size,
                              hipStream_t stream) {
  const float* x       = (const float*)d_in[0];
  const int* ei        = (const int*)d_in[1];   // int32 (harness converts int64 -> int)
  const float* Wl1     = (const float*)d_in[2];
  const float* bl1     = (const float*)d_in[3];
  const float* Wr1     = (const float*)d_in[4];
  const float* br1     = (const float*)d_in[5];
  const float* att1    = (const float*)d_in[6];
  const float* b1      = (const float*)d_in[7];
  const float* Wl2     = (const float*)d_in[8];
  const float* bl2     = (const float*)d_in[9];
  const float* Wr2     = (const float*)d_in[10];
  const float* br2     = (const float*)d_in[11];
  const float* att2    = (const float*)d_in[12];
  const float* b2      = (const float*)d_in[13];
  const float* skip1_w = (const float*)d_in[14];
  const float* skip1_b = (const float*)d_in[15];
  const float* skip2_w = (const float*)d_in[16];
  const float* skip2_b = (const float*)d_in[17];
  const float* mlp1_w  = (const float*)d_in[18];
  const float* mlp1_b  = (const float*)d_in[19];
  const float* mlp2_w  = (const float*)d_in[20];
  const float* mlp2_b  = (const float*)d_in[21];

  const int N = in_sizes[0] / 128;
  const int E = in_sizes[1] / 2;
  float* out = (float*)d_out;

  char* ws = (char*)d_ws;
  size_t off = 0;
  auto alloc = [&](size_t bytes) -> void* {
    void* p = ws + off;
    off = (off + bytes + 255) & ~(size_t)255;
    return p;
  };
  int* rowptr  = (int*)alloc((size_t)(N + 1) * sizeof(int));
  int* cnt     = (int*)alloc((size_t)N * sizeof(int));
  int* csr_src = (int*)alloc((size_t)E * sizeof(int));
  float* bufA  = (float*)alloc((size_t)N * 128 * sizeof(float));
  float* bufB  = (float*)alloc((size_t)N * 128 * sizeof(float));
  float* bufC  = (float*)alloc((size_t)N * 128 * sizeof(float));

  const int* srcp = ei;
  const int* dstp = ei + E;

  const int egrid = (E + 255) / 256;
  const int ggrid = (N + 63) / 64;
  const int agrid = (N + 3) / 4;

  // CSR by dst (shared by both GAT layers)
  hipMemsetAsync(cnt, 0, (size_t)N * sizeof(int), stream);
  count_kernel<<<egrid, 256, 0, stream>>>(dstp, cnt, E);
  scan_kernel<<<1, 1024, 0, stream>>>(cnt, rowptr, N);
  hipMemsetAsync(cnt, 0, (size_t)N * sizeof(int), stream);
  fill_kernel<<<egrid, 256, 0, stream>>>(srcp, dstp, rowptr, cnt, csr_src, E);

  // ---- Layer 1: GATv2(128 -> 4x32 concat) + skip + ReLU ----
  gemm_k128<128, false><<<ggrid, 256, 0, stream>>>(x, Wl1, bl1, bufA, N);      // xl1
  gemm_k128<128, false><<<ggrid, 256, 0, stream>>>(x, Wr1, br1, bufB, N);      // xr1
  gemm_k128<128, false><<<ggrid, 256, 0, stream>>>(x, skip1_w, skip1_b, bufC, N); // skip1
  gat_agg<4><<<agrid, 256, 0, stream>>>(bufA, bufB, bufC, att1, b1,
                                        rowptr, csr_src, bufC, N, 1);          // h -> bufC

  // ---- Layer 2: GATv2(128 -> 128, 1 head) + skip ----
  gemm_k128<128, false><<<ggrid, 256, 0, stream>>>(bufC, Wl2, bl2, bufA, N);   // xl2
  gemm_k128<128, false><<<ggrid, 256, 0, stream>>>(bufC, Wr2, br2, bufB, N);   // xr2
  gemm_k128<128, false><<<ggrid, 256, 0, stream>>>(bufC, skip2_w, skip2_b, bufC, N); // skip2 in-place
  gat_agg<1><<<agrid, 256, 0, stream>>>(bufA, bufB, bufC, att2, b2,
                                        rowptr, csr_src, bufC, N, 0);          // out2 -> bufC

  // ---- MLP head ----
  gemm_k128<128, true><<<ggrid, 256, 0, stream>>>(bufC, mlp1_w, mlp1_b, bufA, N);
  gemm_k128<64, false><<<ggrid, 256, 0, stream>>>(bufA, mlp2_w, mlp2_b, out, N);
}

// Round 4
// 863.775 us; speedup vs baseline: 1.4088x; 1.1376x over previous
//
#include <hip/hip_runtime.h>

#define LEAK 0.2f

// ---------------- CSR build (incoming edges per dst) ----------------
__global__ void count_kernel(const int* __restrict__ dstp, int* __restrict__ cnt, int E) {
  int e = blockIdx.x * blockDim.x + threadIdx.x;
  if (e < E) atomicAdd(&cnt[dstp[e]], 1);
}

// Two-level scan, all coalesced.
// A: per-1024-block inclusive scan (LDS Hillis-Steele) + block sums
__global__ __launch_bounds__(1024)
void scan_blocks(const int* __restrict__ cnt, int* __restrict__ tscan,
                 int* __restrict__ bsum, int n) {
  __shared__ int sh[1024];
  int t = threadIdx.x;
  int i = blockIdx.x * 1024 + t;
  sh[t] = (i < n) ? cnt[i] : 0;
  __syncthreads();
  for (int off = 1; off < 1024; off <<= 1) {
    int u = (t >= off) ? sh[t - off] : 0;
    __syncthreads();
    sh[t] += u;
    __syncthreads();
  }
  if (i < n) tscan[i] = sh[t];
  if (t == 1023) bsum[blockIdx.x] = sh[1023];
}

// B: scan the block sums (nb <= 1024), write total to rowptr[n]
__global__ __launch_bounds__(1024)
void scan_bsums(int* __restrict__ bsum, int* __restrict__ rowptr, int nb, int n) {
  __shared__ int sh[1024];
  int t = threadIdx.x;
  sh[t] = (t < nb) ? bsum[t] : 0;
  __syncthreads();
  for (int off = 1; off < 1024; off <<= 1) {
    int u = (t >= off) ? sh[t - off] : 0;
    __syncthreads();
    sh[t] += u;
    __syncthreads();
  }
  if (t < nb) bsum[t] = sh[t];  // inclusive in place
  if (t == nb - 1) rowptr[n] = sh[t];
}

// C: rowptr[i] = block_prefix + inclusive[i] - cnt[i]  (exclusive scan)
__global__ __launch_bounds__(1024)
void scan_final(const int* __restrict__ cnt, const int* __restrict__ tscan,
                const int* __restrict__ bsum, int* __restrict__ rowptr, int n) {
  int i = blockIdx.x * 1024 + threadIdx.x;
  if (i < n) {
    int bpref = (blockIdx.x == 0) ? 0 : bsum[blockIdx.x - 1];
    rowptr[i] = bpref + tscan[i] - cnt[i];
  }
}

__global__ void fill_kernel(const int* __restrict__ srcp, const int* __restrict__ dstp,
                            const int* __restrict__ rowptr, int* __restrict__ cur,
                            int* __restrict__ csr_src, int E) {
  int e = blockIdx.x * blockDim.x + threadIdx.x;
  if (e < E) {
    int d = dstp[e];
    int pos = atomicAdd(&cur[d], 1);
    csr_src[rowptr[d] + pos] = srcp[e];
  }
}

// ---------- GEMM: C[M,NOUT] = A[M,128] @ W[128,NOUT] + bias, optional ReLU ----------
// W staged in LDS in two 64-k chunks (32 KB for NOUT=128) -> 5 blocks/CU (20
// waves/CU). A read direct from global (block's 64x128 tile = 32KB, L1-resident;
// 16 lanes broadcast-coalesce). In-place safe (C==A): each block reads only rows
// it writes; chunk-end __syncthreads() fences all A reads before the C write.
template<int NOUT, bool RELU>
__global__ __launch_bounds__(256)
void gemm_k128(const float* __restrict__ A, const float* __restrict__ W,
               const float* __restrict__ bias, float* __restrict__ C, int M) {
  constexpr int TN = NOUT / 16;  // 8 (NOUT=128) or 4 (NOUT=64)
  constexpr int KC = 64;
  __shared__ float Ws[KC * NOUT];
  int tid = threadIdx.x;
  int row0 = blockIdx.x * 64;
  int rg = tid >> 4, cg = tid & 15;
  int r[4];
#pragma unroll
  for (int i = 0; i < 4; ++i) { int rr = row0 + rg * 4 + i; r[i] = rr < M ? rr : M - 1; }

  float acc[4][TN];
#pragma unroll
  for (int i = 0; i < 4; ++i)
#pragma unroll
    for (int j = 0; j < TN; ++j) acc[i][j] = 0.f;

  for (int kc = 0; kc < 128; kc += KC) {
    for (int i = tid * 4; i < KC * NOUT; i += 256 * 4)
      *(float4*)&Ws[i] = *(const float4*)&W[kc * NOUT + i];
    __syncthreads();

#pragma unroll 4
    for (int k4 = 0; k4 < KC / 4; ++k4) {
      float4 a[4];
#pragma unroll
      for (int i = 0; i < 4; ++i) a[i] = *(const float4*)&A[(size_t)r[i] * 128 + kc + k4 * 4];
#pragma unroll
      for (int kk = 0; kk < 4; ++kk) {
        float b[TN];
#pragma unroll
        for (int j4 = 0; j4 < TN / 4; ++j4)
          *(float4*)&b[j4 * 4] = *(const float4*)&Ws[(k4 * 4 + kk) * NOUT + cg * TN + j4 * 4];
#pragma unroll
        for (int i = 0; i < 4; ++i) {
          float av = ((const float*)&a[i])[kk];
#pragma unroll
          for (int j = 0; j < TN; ++j) acc[i][j] += av * b[j];
        }
      }
    }
    __syncthreads();  // fences A reads of this chunk; also before restage
  }

  float bv[TN];
#pragma unroll
  for (int j4 = 0; j4 < TN / 4; ++j4)
    *(float4*)&bv[j4 * 4] = *(const float4*)&bias[cg * TN + j4 * 4];

#pragma unroll
  for (int i = 0; i < 4; ++i) {
    int rr = row0 + rg * 4 + i;
    if (rr < M) {
#pragma unroll
      for (int j4 = 0; j4 < TN / 4; ++j4) {
        float4 o;
        float* op = (float*)&o;
#pragma unroll
        for (int q = 0; q < 4; ++q) {
          float v = acc[i][j4 * 4 + q] + bv[j4 * 4 + q];
          if (RELU) v = fmaxf(v, 0.f);
          op[q] = v;
        }
        *(float4*)&C[(size_t)rr * NOUT + cg * TN + j4 * 4] = o;
      }
    }
  }
}

// ---------- GATv2 aggregation: one wave per node, 4 edges in flight ----------
template<int H>
__global__ __launch_bounds__(256)
void gat_agg(const float* __restrict__ xl, const float* __restrict__ xr,
             const float* __restrict__ skip, const float* __restrict__ att,
             const float* __restrict__ gbias, const int* __restrict__ rowptr,
             const int* __restrict__ csr_src, float* __restrict__ out,
             int n, int relu) {
  constexpr int C = 128 / H;  // channels per head
  constexpr int G = C / 2;    // lanes per head-group (2 floats/lane)
  int wid = blockIdx.x * (blockDim.x >> 6) + (threadIdx.x >> 6);
  if (wid >= n) return;
  int lane = threadIdx.x & 63;
  size_t base = (size_t)wid * 128 + lane * 2;
  float2 xrv = *(const float2*)(xr + base);
  float2 av = *(const float2*)(att + lane * 2);  // att flat [H*C]=[128]
  float2 acc = make_float2(0.f, 0.f);
  float denom = 0.f;
  int e0 = rowptr[wid], e1 = rowptr[wid + 1];

  // self-loop
  {
    float2 xlv = *(const float2*)(xl + base);
    float ex = xlv.x + xrv.x; ex = ex > 0.f ? ex : LEAK * ex;
    float ey = xlv.y + xrv.y; ey = ey > 0.f ? ey : LEAK * ey;
    float p = ex * av.x + ey * av.y;
#pragma unroll
    for (int o = 1; o < G; o <<= 1) p += __shfl_xor(p, o, 64);
    float w = __expf(p);
    denom += w;
    acc.x += w * xlv.x;
    acc.y += w * xlv.y;
  }

  int idx = e0;
  for (; idx + 4 <= e1; idx += 4) {
    int s0 = csr_src[idx], s1 = csr_src[idx + 1], s2 = csr_src[idx + 2], s3 = csr_src[idx + 3];
    float2 v0 = *(const float2*)(xl + (size_t)s0 * 128 + lane * 2);
    float2 v1 = *(const float2*)(xl + (size_t)s1 * 128 + lane * 2);
    float2 v2 = *(const float2*)(xl + (size_t)s2 * 128 + lane * 2);
    float2 v3 = *(const float2*)(xl + (size_t)s3 * 128 + lane * 2);
    float ex, ey;
    ex = v0.x + xrv.x; ex = ex > 0.f ? ex : LEAK * ex;
    ey = v0.y + xrv.y; ey = ey > 0.f ? ey : LEAK * ey;
    float p0 = ex * av.x + ey * av.y;
    ex = v1.x + xrv.x; ex = ex > 0.f ? ex : LEAK * ex;
    ey = v1.y + xrv.y; ey = ey > 0.f ? ey : LEAK * ey;
    float p1 = ex * av.x + ey * av.y;
    ex = v2.x + xrv.x; ex = ex > 0.f ? ex : LEAK * ex;
    ey = v2.y + xrv.y; ey = ey > 0.f ? ey : LEAK * ey;
    float p2 = ex * av.x + ey * av.y;
    ex = v3.x + xrv.x; ex = ex > 0.f ? ex : LEAK * ex;
    ey = v3.y + xrv.y; ey = ey > 0.f ? ey : LEAK * ey;
    float p3 = ex * av.x + ey * av.y;
#pragma unroll
    for (int o = 1; o < G; o <<= 1) {
      p0 += __shfl_xor(p0, o, 64);
      p1 += __shfl_xor(p1, o, 64);
      p2 += __shfl_xor(p2, o, 64);
      p3 += __shfl_xor(p3, o, 64);
    }
    float w0 = __expf(p0), w1 = __expf(p1), w2 = __expf(p2), w3 = __expf(p3);
    denom += (w0 + w1) + (w2 + w3);
    acc.x += w0 * v0.x + w1 * v1.x + w2 * v2.x + w3 * v3.x;
    acc.y += w0 * v0.y + w1 * v1.y + w2 * v2.y + w3 * v3.y;
  }
  for (; idx < e1; ++idx) {
    int src = csr_src[idx];
    float2 xlv = *(const float2*)(xl + (size_t)src * 128 + lane * 2);
    float ex = xlv.x + xrv.x; ex = ex > 0.f ? ex : LEAK * ex;
    float ey = xlv.y + xrv.y; ey = ey > 0.f ? ey : LEAK * ey;
    float p = ex * av.x + ey * av.y;
#pragma unroll
    for (int o = 1; o < G; o <<= 1) p += __shfl_xor(p, o, 64);
    float w = __expf(p);
    denom += w;
    acc.x += w * xlv.x;
    acc.y += w * xlv.y;
  }

  float inv = 1.f / denom;
  float2 sk = *(const float2*)(skip + base);
  float2 gb = *(const float2*)(gbias + lane * 2);
  float ox = acc.x * inv + gb.x + sk.x;
  float oy = acc.y * inv + gb.y + sk.y;
  if (relu) { ox = fmaxf(ox, 0.f); oy = fmaxf(oy, 0.f); }
  *(float2*)(out + base) = make_float2(ox, oy);
}

extern "C" void kernel_launch(void* const* d_in, const int* in_sizes, int n_in,
                              void* d_out, int out_size, void* d_ws, size_t ws_size,
                              hipStream_t stream) {
  const float* x       = (const float*)d_in[0];
  const int* ei        = (const int*)d_in[1];   // int32 (harness converts int64 -> int)
  const float* Wl1     = (const float*)d_in[2];
  const float* bl1     = (const float*)d_in[3];
  const float* Wr1     = (const float*)d_in[4];
  const float* br1     = (const float*)d_in[5];
  const float* att1    = (const float*)d_in[6];
  const float* b1      = (const float*)d_in[7];
  const float* Wl2     = (const float*)d_in[8];
  const float* bl2     = (const float*)d_in[9];
  const float* Wr2     = (const float*)d_in[10];
  const float* br2     = (const float*)d_in[11];
  const float* att2    = (const float*)d_in[12];
  const float* b2      = (const float*)d_in[13];
  const float* skip1_w = (const float*)d_in[14];
  const float* skip1_b = (const float*)d_in[15];
  const float* skip2_w = (const float*)d_in[16];
  const float* skip2_b = (const float*)d_in[17];
  const float* mlp1_w  = (const float*)d_in[18];
  const float* mlp1_b  = (const float*)d_in[19];
  const float* mlp2_w  = (const float*)d_in[20];
  const float* mlp2_b  = (const float*)d_in[21];

  const int N = in_sizes[0] / 128;
  const int E = in_sizes[1] / 2;
  float* out = (float*)d_out;

  char* ws = (char*)d_ws;
  size_t off = 0;
  auto alloc = [&](size_t bytes) -> void* {
    void* p = ws + off;
    off = (off + bytes + 255) & ~(size_t)255;
    return p;
  };
  int* rowptr  = (int*)alloc((size_t)(N + 1) * sizeof(int));
  int* cnt     = (int*)alloc((size_t)N * sizeof(int));
  int* tscan   = (int*)alloc((size_t)N * sizeof(int));
  int* bsum    = (int*)alloc((size_t)1024 * sizeof(int));
  int* csr_src = (int*)alloc((size_t)E * sizeof(int));
  float* bufA  = (float*)alloc((size_t)N * 128 * sizeof(float));
  float* bufB  = (float*)alloc((size_t)N * 128 * sizeof(float));
  float* bufC  = (float*)alloc((size_t)N * 128 * sizeof(float));

  const int* srcp = ei;
  const int* dstp = ei + E;

  const int egrid = (E + 255) / 256;
  const int ggrid = (N + 63) / 64;
  const int agrid = (N + 3) / 4;
  const int nb = (N + 1023) / 1024;

  // CSR by dst (shared by both GAT layers)
  hipMemsetAsync(cnt, 0, (size_t)N * sizeof(int), stream);
  count_kernel<<<egrid, 256, 0, stream>>>(dstp, cnt, E);
  scan_blocks<<<nb, 1024, 0, stream>>>(cnt, tscan, bsum, N);
  scan_bsums<<<1, 1024, 0, stream>>>(bsum, rowptr, nb, N);
  scan_final<<<nb, 1024, 0, stream>>>(cnt, tscan, bsum, rowptr, N);
  hipMemsetAsync(cnt, 0, (size_t)N * sizeof(int), stream);
  fill_kernel<<<egrid, 256, 0, stream>>>(srcp, dstp, rowptr, cnt, csr_src, E);

  // ---- Layer 1: GATv2(128 -> 4x32 concat) + skip + ReLU ----
  gemm_k128<128, false><<<ggrid, 256, 0, stream>>>(x, Wl1, bl1, bufA, N);      // xl1
  gemm_k128<128, false><<<ggrid, 256, 0, stream>>>(x, Wr1, br1, bufB, N);      // xr1
  gemm_k128<128, false><<<ggrid, 256, 0, stream>>>(x, skip1_w, skip1_b, bufC, N); // skip1
  gat_agg<4><<<agrid, 256, 0, stream>>>(bufA, bufB, bufC, att1, b1,
                                        rowptr, csr_src, bufC, N, 1);          // h -> bufC

  // ---- Layer 2: GATv2(128 -> 128, 1 head) + skip ----
  gemm_k128<128, false><<<ggrid, 256, 0, stream>>>(bufC, Wl2, bl2, bufA, N);   // xl2
  gemm_k128<128, false><<<ggrid, 256, 0, stream>>>(bufC, Wr2, br2, bufB, N);   // xr2
  gemm_k128<128, false><<<ggrid, 256, 0, stream>>>(bufC, skip2_w, skip2_b, bufC, N); // skip2 in-place
  gat_agg<1><<<agrid, 256, 0, stream>>>(bufA, bufB, bufC, att2, b2,
                                        rowptr, csr_src, bufC, N, 0);          // out2 -> bufC

  // ---- MLP head ----
  gemm_k128<128, true><<<ggrid, 256, 0, stream>>>(bufC, mlp1_w, mlp1_b, bufA, N);
  gemm_k128<64, false><<<ggrid, 256, 0, stream>>>(bufA, mlp2_w, mlp2_b, out, N);
}